// Round 11
// baseline (180.821 us; speedup 1.0000x reference)
//
#include <hip/hip_runtime.h>

typedef unsigned short u16;
typedef unsigned int   u32;
typedef short bf16x8 __attribute__((ext_vector_type(8)));
typedef float f32x16 __attribute__((ext_vector_type(16)));

#define S_  2048
#define D_  64
#define NR_ 4
#define NB_ 32

#define AS 72    // A tile row stride (shorts), 144 B (16B-aligned)
#define VS 136   // Vt row stride (shorts), 272 B
#define PS 136   // SM row stride (shorts), 272 B

__device__ __forceinline__ float bf2f(u16 u){ return __uint_as_float(((u32)u)<<16); }
__device__ __forceinline__ u16 f2bf(float f){
  u32 u = __float_as_uint(f);
  u32 r = (u + 0x7fffu + ((u>>16)&1u)) >> 16;
  return (u16)r;
}
// packed f32x2 -> bf16x2 (RNE). gfx950 has v_cvt_pk_bf16_f32.
__device__ __forceinline__ u32 pk2bf(float a, float b){
#if __has_builtin(__builtin_amdgcn_cvt_pk_bf16_f32)
  auto r = __builtin_amdgcn_cvt_pk_bf16_f32(a, b);
  u32 u; __builtin_memcpy(&u, &r, 4); return u;
#else
  return (u32)f2bf(a) | ((u32)f2bf(b) << 16);
#endif
}
__device__ __forceinline__ u16 f2bf1(float a){ return (u16)pk2bf(a, a); }
__device__ __forceinline__ void unpack2(u32 w, float &a, float &b){
  a = __uint_as_float(w<<16);
  b = __uint_as_float(w & 0xffff0000u);
}
__device__ __forceinline__ bf16x8 ld8(const u16* p){
  union { uint4 u; bf16x8 v; } x;
  x.u = *(const uint4*)p;
  return x.v;
}

// ---------------------------------------------------------------------------
// K1: hash via LDS-broadcast R. Round-split layout: wave w computes ROUND w
// for 256 positions (4 positions/thread, 16 R-columns each). acc stays at
// 4x16 = 64 VGPRs — the proven no-spill budget (the RA refuses >128 VGPRs
// for this kernel shape and spills catastrophically: R4/R5/R6/R9). DS
// instructions drop 4x vs the all-rounds-per-thread shape (256 vs 1024
// ds_read_b128/thread; 16 FMA/read). Per-output FMA order (c,dd) unchanged
// -> argmax bit-identical. Wave 0 also emits q->bf16+scq, wave 1 v->bf16
// (wave-uniform branches, VMEM overlapped with DS/VALU).
// ---------------------------------------------------------------------------
__global__ __launch_bounds__(256, 2) void k_hash(const float* __restrict__ q,
                                                 const float* __restrict__ v,
                                                 const float* __restrict__ R,
                                                 int* __restrict__ hout,
                                                 u16* __restrict__ qb,
                                                 u16* __restrict__ vbuf,
                                                 float* __restrict__ scq){
  __shared__ float Rl[4096];               // [d][r*16+k] row-major, f32
  int b    = blockIdx.x >> 3;
  int pbas = (blockIdx.x & 7) * 256;
  int t    = threadIdx.x;
  int w    = t >> 6;                       // wave = round
  int lane = t & 63;

  { // stage R (coalesced)
    const float4* Rg = (const float4*)(R + (size_t)b * 4096);
    float4* Rs = (float4*)Rl;
    #pragma unroll
    for (int k = 0; k < 4; k++) Rs[k*256 + t] = Rg[k*256 + t];
  }
  __syncthreads();

  // 4 positions per thread: pbas + i*64 + lane
  const float4* q4[4];
  const float4* v4[4];
  uint2* qw[4];
  uint2* vw[4];
  int pos[4];
  #pragma unroll
  for (int i = 0; i < 4; i++){
    pos[i] = pbas + i*64 + lane;
    size_t off = ((size_t)b * S_ + pos[i]) * D_;
    q4[i] = (const float4*)(q + off);
    v4[i] = (const float4*)(v + off);
    qw[i] = (uint2*)(qb   + off);
    vw[i] = (uint2*)(vbuf + off);
  }

  float acc[4][16];                        // 4 positions x 16 cols (round w)
  #pragma unroll
  for (int i = 0; i < 4; i++)
    #pragma unroll
    for (int k = 0; k < 16; k++) acc[i][k] = 0.f;
  float ss[4] = {0.f, 0.f, 0.f, 0.f};

  #pragma unroll 2
  for (int c = 0; c < 16; c++){
    float4 qv[4];
    #pragma unroll
    for (int i = 0; i < 4; i++) qv[i] = q4[i][c];
    if (w == 0){                           // wave-uniform
      #pragma unroll
      for (int i = 0; i < 4; i++){
        float4 f = qv[i];
        ss[i] += f.x*f.x + f.y*f.y + f.z*f.z + f.w*f.w;
        qw[i][c] = make_uint2(pk2bf(f.x, f.y), pk2bf(f.z, f.w));
      }
    } else if (w == 1){
      #pragma unroll
      for (int i = 0; i < 4; i++){
        float4 x = v4[i][c];
        vw[i][c] = make_uint2(pk2bf(x.x, x.y), pk2bf(x.z, x.w));
      }
    }
    #pragma unroll
    for (int dd = 0; dd < 4; dd++){
      int d = c * 4 + dd;
      const float4* Rr = (const float4*)(&Rl[d * 64 + w * 16]);
      #pragma unroll
      for (int k4 = 0; k4 < 4; k4++){
        float4 rv = Rr[k4];    // all 64 lanes same addr — conflict-free
        #pragma unroll
        for (int i = 0; i < 4; i++){
          float qa = (dd == 0) ? qv[i].x : (dd == 1) ? qv[i].y
                   : (dd == 2) ? qv[i].z : qv[i].w;
          acc[i][k4*4+0] += qa * rv.x;
          acc[i][k4*4+1] += qa * rv.y;
          acc[i][k4*4+2] += qa * rv.z;
          acc[i][k4*4+3] += qa * rv.w;
        }
      }
    }
  }
  if (w == 0){
    #pragma unroll
    for (int i = 0; i < 4; i++)
      scq[(size_t)b * S_ + pos[i]] = rsqrtf(fmaxf(ss[i], 1e-12f)) * 0.125f;
  }

  #pragma unroll
  for (int i = 0; i < 4; i++){
    float bv = acc[i][0]; int bi = 0;
    #pragma unroll
    for (int m = 1; m < 32; m++){
      float vv = (m < 16) ? acc[i][m] : -acc[i][m - 16];
      if (vv > bv){ bv = vv; bi = m; }   // strict >: first max wins
    }
    hout[((size_t)b * NR_ + w) * S_ + pos[i]] = bi;
  }
}

// ---------------------------------------------------------------------------
// K2: stable counting sort on 32 bins per (b,r).
// ---------------------------------------------------------------------------
__global__ __launch_bounds__(256) void k_sort(const int* __restrict__ h,
                                              int* __restrict__ sidx,
                                              int* __restrict__ chk){
  __shared__ int cnt[32][257];
  __shared__ int base[32];
  int br = blockIdx.x;
  const int* hb = h + (size_t)br * S_;
  int t = threadIdx.x;

  #pragma unroll
  for (int hh = 0; hh < 32; hh++) cnt[hh][t] = 0;
  __syncthreads();

  int hv[8];
  const int4* hb4 = (const int4*)hb;
  int4 a0 = hb4[t*2], a1 = hb4[t*2+1];
  hv[0]=a0.x; hv[1]=a0.y; hv[2]=a0.z; hv[3]=a0.w;
  hv[4]=a1.x; hv[5]=a1.y; hv[6]=a1.z; hv[7]=a1.w;
  #pragma unroll
  for (int k = 0; k < 8; k++) cnt[hv[k]][t]++;
  __syncthreads();

  int wave = t >> 6, lane = t & 63;
  for (int hh = wave*8; hh < wave*8 + 8; hh++){
    int vals[4]; int s0 = 0;
    #pragma unroll
    for (int k = 0; k < 4; k++){ vals[k] = cnt[hh][lane*4+k]; s0 += vals[k]; }
    int incl = s0;
    #pragma unroll
    for (int off = 1; off < 64; off <<= 1){
      int o = __shfl_up(incl, off, 64);
      if (lane >= off) incl += o;
    }
    int run = incl - s0;
    #pragma unroll
    for (int k = 0; k < 4; k++){ int tmp = vals[k]; cnt[hh][lane*4+k] = run; run += tmp; }
    if (lane == 63) base[hh] = incl;
  }
  __syncthreads();
  if (t == 0){
    int run = 0;
    #pragma unroll
    for (int hh = 0; hh < 32; hh++){ int tot = base[hh]; base[hh] = run; run += tot; }
  }
  __syncthreads();

  int p0 = t * 8;
  #pragma unroll
  for (int k = 0; k < 8; k++){
    int hh = hv[k];
    int c = cnt[hh][t];
    int slot = base[hh] + c;
    cnt[hh][t] = c + 1;
    sidx[(size_t)br * S_ + slot]    = p0 + k;
    chk [(size_t)br * S_ + p0 + k]  = slot >> 6;
  }
}

// ---------------------------------------------------------------------------
// K3: per (b, r, bucket n): MFMA attention on pre-converted bf16 q/v.
// S^T via MFMA (col=i query, regs=j keys): softmax runs entirely on the f32
// accumulators in registers (no logit LDS round-trip); per-(i,jtile) partial
// (max,sum) reduced via shfl + 4x64 LDS arrays; probs written to SM once.
// Phase 5 computes out^T (Vt rows A, P rows B) -> vectorized scatter.
// ---------------------------------------------------------------------------
__global__ __launch_bounds__(256, 3) void k_attn(const u16* __restrict__ qb,
                                                 const u16* __restrict__ vb,
                                                 const int* __restrict__ sidx,
                                                 const int* __restrict__ chk,
                                                 const float* __restrict__ scq,
                                                 float* __restrict__ lse_ws,
                                                 u16*  __restrict__ att_ws){
  __shared__ u16 A[128*AS];      // Q/K tile row-major; later Vt[64][VS] (d-major)
  __shared__ u16 SM[64*PS];      // probabilities (bf16), row i, col j
  __shared__ int   pkey[128];
  __shared__ float rcnt[128];
  __shared__ float sc[128];
  __shared__ float pm[4*64];     // per (jtile, i) partial max
  __shared__ float ps[4*64];     // per (jtile, i) partial sum

  int blk = blockIdx.x;
  int b = blk >> 7, r = (blk >> 5) & 3, n = blk & 31;
  int npv = (n + 31) & 31;
  int t = threadIdx.x;
  int lane = t & 63, w = t >> 6;
  int la = lane & 31, hh = lane >> 5;
  int coff = hh * 8;
  const int* sb = sidx + ((size_t)b * NR_ + r) * S_;

  if (t < 128){
    int p = (t < 64) ? sb[npv*64 + t] : sb[n*64 + (t - 64)];
    pkey[t] = p;
    int c = 0;
    #pragma unroll
    for (int rr = 0; rr < 4; rr++){
      int ch = chk[((size_t)b * NR_ + rr) * S_ + p];
      c += (ch == n) || (ch == npv);
    }
    if (c < 1) c = 1;
    rcnt[t] = 1.0f / (float)c;
    sc[t] = scq[(size_t)b * S_ + p];
  }
  __syncthreads();

  // ---- phase 1: stage Q/K bf16 rows; early V column gather ----------------
  {
    int row = t >> 1, half = t & 1;
    const uint4* src = (const uint4*)(qb + ((size_t)b*S_ + pkey[row])*D_) + half*4;
    uint4* dst = (uint4*)(&A[row*AS + half*32]);
    #pragma unroll
    for (int k = 0; k < 4; k++) dst[k] = src[k];
  }
  int jp = t & 63, dgrp = t >> 6;   // V: key pair (2jp,2jp+1), d-range dgrp*16..+15
  uint4 va0, va1, vb0, vb1;
  {
    const uint4* s0 = (const uint4*)(vb + ((size_t)b*S_ + pkey[2*jp  ])*D_ + dgrp*16);
    const uint4* s1 = (const uint4*)(vb + ((size_t)b*S_ + pkey[2*jp+1])*D_ + dgrp*16);
    va0 = s0[0]; va1 = s0[1]; vb0 = s1[0]; vb1 = s1[1];
  }
  __syncthreads();

  // ---- phase 2: S^T = K.Q^T via MFMA; mask+exp in registers; partials -----
  float e0[16], e1[16];            // exp(x - m_loc), live across the barrier
  float ml0, ml1;                  // per-lane local maxima
  {
    int jt = w;                         // j-tile 0..3
    f32x16 acc0, acc1;                  // i = la, i = 32+la
    #pragma unroll
    for (int i = 0; i < 16; i++){ acc0[i] = 0.f; acc1[i] = 0.f; }
    int arow  = (jt*32 + la) * AS;      // K row j
    int brow0 = (64 + la) * AS;         // Q row i (0..31)
    int brow1 = (96 + la) * AS;         // Q row i (32..63)
    #pragma unroll
    for (int ks = 0; ks < 4; ks++){
      int o = ks*16 + coff;
      bf16x8 af = ld8(&A[arow  + o]);
      bf16x8 b0 = ld8(&A[brow0 + o]);
      bf16x8 b1 = ld8(&A[brow1 + o]);
      acc0 = __builtin_amdgcn_mfma_f32_32x32x16_bf16(af, b0, acc0, 0, 0, 0);
      acc1 = __builtin_amdgcn_mfma_f32_32x32x16_bf16(af, b1, acc1, 0, 0, 0);
    }
    int pj[16]; float scj[16];
    #pragma unroll
    for (int g = 0; g < 4; g++){
      int j0 = jt*32 + g*8 + 4*hh;
      #pragma unroll
      for (int m = 0; m < 4; m++){ pj[g*4+m] = pkey[j0+m]; scj[g*4+m] = sc[j0+m]; }
    }
    int pi0 = pkey[64 + la], pi1 = pkey[96 + la];
    float x0[16], x1[16];
    #pragma unroll
    for (int reg = 0; reg < 16; reg++){
      float a0v = acc0[reg] * scj[reg];
      float a1v = acc1[reg] * scj[reg];
      if (pi0 < pj[reg]) a0v = -1000000000.0f; else if (pi0 == pj[reg]) a0v = -100000.0f;
      if (pi1 < pj[reg]) a1v = -1000000000.0f; else if (pi1 == pj[reg]) a1v = -100000.0f;
      x0[reg] = a0v; x1[reg] = a1v;
    }
    ml0 = x0[0]; ml1 = x1[0];
    #pragma unroll
    for (int reg = 1; reg < 16; reg++){ ml0 = fmaxf(ml0, x0[reg]); ml1 = fmaxf(ml1, x1[reg]); }
    float s0 = 0.f, s1 = 0.f;
    #pragma unroll
    for (int reg = 0; reg < 16; reg++){
      e0[reg] = __expf(x0[reg] - ml0); s0 += e0[reg];
      e1[reg] = __expf(x1[reg] - ml1); s1 += e1[reg];
    }
    // combine the two hh halves (same i, disjoint j) within the wave
    float om0 = __shfl_xor(ml0, 32, 64), os0 = __shfl_xor(s0, 32, 64);
    float om1 = __shfl_xor(ml1, 32, 64), os1 = __shfl_xor(s1, 32, 64);
    float m20 = fmaxf(ml0, om0);
    float m21 = fmaxf(ml1, om1);
    float s20 = s0 * __expf(ml0 - m20) + os0 * __expf(om0 - m20);
    float s21 = s1 * __expf(ml1 - m21) + os1 * __expf(om1 - m21);
    if (hh == 0){
      pm[jt*64 + la]      = m20;  ps[jt*64 + la]      = s20;
      pm[jt*64 + 32 + la] = m21;  ps[jt*64 + 32 + la] = s21;
    }
  }
  __syncthreads();

  // ---- phase 3: finalize softmax from partials, write probs; Vt build -----
  {
    int jt = w;
    // global (m, s) for i = la and i = 32+la
    float mg0 = pm[la],      mg1 = pm[32 + la];
    #pragma unroll
    for (int k = 1; k < 4; k++){
      mg0 = fmaxf(mg0, pm[k*64 + la]);
      mg1 = fmaxf(mg1, pm[k*64 + 32 + la]);
    }
    float sg0 = 0.f, sg1 = 0.f;
    #pragma unroll
    for (int k = 0; k < 4; k++){
      sg0 += ps[k*64 + la]      * __expf(pm[k*64 + la]      - mg0);
      sg1 += ps[k*64 + 32 + la] * __expf(pm[k*64 + 32 + la] - mg1);
    }
    float f0 = __expf(ml0 - mg0) / sg0;
    float f1 = __expf(ml1 - mg1) / sg1;
    #pragma unroll
    for (int g = 0; g < 4; g++){
      int j0 = jt*32 + g*8 + 4*hh;
      float4 rc = *(const float4*)(&rcnt[j0]);
      float p00 = e0[g*4+0]*f0*rc.x, p01 = e0[g*4+1]*f0*rc.y;
      float p02 = e0[g*4+2]*f0*rc.z, p03 = e0[g*4+3]*f0*rc.w;
      float p10 = e1[g*4+0]*f1*rc.x, p11 = e1[g*4+1]*f1*rc.y;
      float p12 = e1[g*4+2]*f1*rc.z, p13 = e1[g*4+3]*f1*rc.w;
      *(uint2*)(&SM[la*PS + j0])        = make_uint2(pk2bf(p00,p01), pk2bf(p02,p03));
      *(uint2*)(&SM[(32+la)*PS + j0])   = make_uint2(pk2bf(p10,p11), pk2bf(p12,p13));
    }
    if (w == 0 && hh == 0){
      lse_ws[((size_t)b*S_ + pkey[64 + la])*NR_ + r] = mg0 + __logf(sg0);
      lse_ws[((size_t)b*S_ + pkey[96 + la])*NR_ + r] = mg1 + __logf(sg1);
    }
  }
  { // Vt = V^T (pure bf16 interleave), overwriting A (reads done pre-barrier)
    u32 au[8] = {va0.x, va0.y, va0.z, va0.w, va1.x, va1.y, va1.z, va1.w};
    u32 bu[8] = {vb0.x, vb0.y, vb0.z, vb0.w, vb1.x, vb1.y, vb1.z, vb1.w};
    u32* vtp = (u32*)A;
    #pragma unroll
    for (int k = 0; k < 8; k++){
      int d0 = dgrp*16 + 2*k;
      u32 even = (au[k] & 0xffffu) | (bu[k] << 16);
      u32 odd  = (au[k] >> 16)     | (bu[k] & 0xffff0000u);
      vtp[ d0      * (VS/2) + jp] = even;
      vtp[(d0 + 1) * (VS/2) + jp] = odd;
    }
  }
  __syncthreads();

  // ---- phase 5: out^T = Vt.P^T via MFMA (M=d, N=i), vectorized scatter ----
  {
    int Mt2 = w >> 1, Nt2 = w & 1;
    f32x16 acc;
    #pragma unroll
    for (int i = 0; i < 16; i++) acc[i] = 0.f;
    int arow = (Mt2*32 + la) * VS;      // Vt row d, j contig
    int brow = (Nt2*32 + la) * PS;      // P row i, j contig
    #pragma unroll
    for (int ks = 0; ks < 8; ks++){
      int o = ks*16 + coff;
      bf16x8 af = ld8(&A[arow + o]);
      bf16x8 bf = ld8(&SM[brow + o]);
      acc = __builtin_amdgcn_mfma_f32_32x32x16_bf16(af, bf, acc, 0, 0, 0);
    }
    // C col = i (lane), rows = d (regs, 4 groups of 4 contiguous)
    int i = Nt2*32 + la;
    int p = pkey[64 + i];
    u16* base = att_ws + (((size_t)b*S_ + p)*NR_ + r)*D_ + Mt2*32 + 4*hh;
    #pragma unroll
    for (int g = 0; g < 4; g++){
      uint2 val = make_uint2(pk2bf(acc[4*g+0], acc[4*g+1]),
                             pk2bf(acc[4*g+2], acc[4*g+3]));
      *(uint2*)(base + g*8) = val;
    }
  }
}

// ---------------------------------------------------------------------------
// K4: per position softmax over round LSEs, weighted sum of round outputs.
// 4 outputs per thread (uint2 att reads, float4 out writes). grid 4096.
// ---------------------------------------------------------------------------
__global__ __launch_bounds__(256) void k_comb(const float* __restrict__ lse_ws,
                                              const u16* __restrict__ att_ws,
                                              float* __restrict__ out){
  size_t idx4 = (size_t)blockIdx.x * 256 + threadIdx.x;  // over B*S*D/4
  size_t pd = idx4 >> 4;
  int d0 = (int)(idx4 & 15) * 4;
  float4 lv = *(const float4*)(lse_ws + pd * 4);
  float m = fmaxf(fmaxf(lv.x, lv.y), fmaxf(lv.z, lv.w));
  float e0 = __expf(lv.x - m), e1 = __expf(lv.y - m);
  float e2 = __expf(lv.z - m), e3 = __expf(lv.w - m);
  float inv = 1.0f / (e0 + e1 + e2 + e3);
  e0 *= inv; e1 *= inv; e2 *= inv; e3 *= inv;
  const u16* a = att_ws + pd * 256 + d0;
  uint2 u0 = *(const uint2*)(a);
  uint2 u1 = *(const uint2*)(a + 64);
  uint2 u2 = *(const uint2*)(a + 128);
  uint2 u3 = *(const uint2*)(a + 192);
  float4 o;
  float a0,b0,a1,b1,a2,b2,a3,b3;
  unpack2(u0.x,a0,b0); unpack2(u1.x,a1,b1); unpack2(u2.x,a2,b2); unpack2(u3.x,a3,b3);
  o.x = a0*e0 + a1*e1 + a2*e2 + a3*e3;
  o.y = b0*e0 + b1*e1 + b2*e2 + b3*e3;
  unpack2(u0.y,a0,b0); unpack2(u1.y,a1,b1); unpack2(u2.y,a2,b2); unpack2(u3.y,a3,b3);
  o.z = a0*e0 + a1*e1 + a2*e2 + a3*e3;
  o.w = b0*e0 + b1*e1 + b2*e2 + b3*e3;
  *(float4*)(out + pd * D_ + d0) = o;
}

// ---------------------------------------------------------------------------
extern "C" void kernel_launch(void* const* d_in, const int* in_sizes, int n_in,
                              void* d_out, int out_size, void* d_ws, size_t ws_size,
                              hipStream_t stream){
  const float* q = (const float*)d_in[0];   // (32,2048,64) f32
  const float* v = (const float*)d_in[1];   // (32,2048,64) f32
  const float* R = (const float*)d_in[2];   // (32,64,4,16) f32

  char* w = (char*)d_ws;
  int*   h    = (int*)  (w + 0);                     // 1 MB
  int*   sidx = (int*)  (w + (size_t)(1u << 20));    // 1 MB
  int*   chkA = (int*)  (w + (size_t)(2u << 20));    // 1 MB
  float* lse  = (float*)(w + (size_t)(3u << 20));    // 1 MB
  u16*   att  = (u16*)  (w + (size_t)(4u << 20));    // 32 MB
  u16*   qb   = (u16*)  (w + (size_t)(36u << 20));   // 8 MB bf16 q
  u16*   vbuf = (u16*)  (w + (size_t)(44u << 20));   // 8 MB bf16 v
  float* scq  = (float*)(w + (size_t)(52u << 20));   // 256 KB
  float* out  = (float*)d_out;

  k_hash <<<256,  256, 0, stream>>>(q, v, R, h, qb, vbuf, scq);
  k_sort <<<128,  256, 0, stream>>>(h, sidx, chkA);
  k_attn <<<4096, 256, 0, stream>>>(qb, vbuf, sidx, chkA, scq, lse, att);
  k_comb <<<4096, 256, 0, stream>>>(lse, att, out);
}

// Round 12
// 147.968 us; speedup vs baseline: 1.2220x; 1.2220x over previous
//
#include <hip/hip_runtime.h>

typedef unsigned short u16;
typedef unsigned int   u32;
typedef short bf16x8 __attribute__((ext_vector_type(8)));
typedef float f32x16 __attribute__((ext_vector_type(16)));

#define S_  2048
#define D_  64
#define NR_ 4
#define NB_ 32

#define AS 72    // A tile row stride (shorts), 144 B (16B-aligned)
#define VS 136   // Vt row stride (shorts), 272 B
#define PS 136   // SM row stride (shorts), 272 B

__device__ __forceinline__ float bf2f(u16 u){ return __uint_as_float(((u32)u)<<16); }
__device__ __forceinline__ u16 f2bf(float f){
  u32 u = __float_as_uint(f);
  u32 r = (u + 0x7fffu + ((u>>16)&1u)) >> 16;
  return (u16)r;
}
// packed f32x2 -> bf16x2 (RNE). gfx950 has v_cvt_pk_bf16_f32.
__device__ __forceinline__ u32 pk2bf(float a, float b){
#if __has_builtin(__builtin_amdgcn_cvt_pk_bf16_f32)
  auto r = __builtin_amdgcn_cvt_pk_bf16_f32(a, b);
  u32 u; __builtin_memcpy(&u, &r, 4); return u;
#else
  return (u32)f2bf(a) | ((u32)f2bf(b) << 16);
#endif
}
__device__ __forceinline__ u16 f2bf1(float a){ return (u16)pk2bf(a, a); }
__device__ __forceinline__ void unpack2(u32 w, float &a, float &b){
  a = __uint_as_float(w<<16);
  b = __uint_as_float(w & 0xffff0000u);
}
__device__ __forceinline__ bf16x8 ld8(const u16* p){
  union { uint4 u; bf16x8 v; } x;
  x.u = *(const uint4*)p;
  return x.v;
}

// ---------------------------------------------------------------------------
// K1: hash via LDS-broadcast R, 1 position/thread, acc[64]. PROVEN SHAPE (R8/
// R10 ~20us) — both alternatives measured WORSE:
//  (a) >64 accumulators (2-pos or 2-pos/2-round): RA caps this kernel at 128
//      VGPRs regardless of __launch_bounds__ and spills to scratch
//      (R4/R5/R6/R9; R9: 296MB FETCH of spill traffic, 195us).
//  (b) round-split waves (4 pos/thread, 16 cols): 4 waves re-read the same
//      q rows; 128KB/block footprint thrashes L1+L2 -> 140MB HBM FETCH,
//      memory-latency-bound 61us (R11).
// Fused q->bf16, v->bf16, scq. DS-broadcast floor ~20us.
// ---------------------------------------------------------------------------
__global__ __launch_bounds__(256, 2) void k_hash(const float* __restrict__ q,
                                                 const float* __restrict__ v,
                                                 const float* __restrict__ R,
                                                 int* __restrict__ hout,
                                                 u16* __restrict__ qb,
                                                 u16* __restrict__ vbuf,
                                                 float* __restrict__ scq){
  __shared__ float Rl[4096];               // [d][r*16+k] row-major, f32
  int b   = blockIdx.x >> 3;
  int pos = (blockIdx.x & 7) * 256 + threadIdx.x;

  { // stage R (coalesced)
    const float4* Rg = (const float4*)(R + (size_t)b * 4096);
    float4* Rs = (float4*)Rl;
    #pragma unroll
    for (int k = 0; k < 4; k++) Rs[k*256 + threadIdx.x] = Rg[k*256 + threadIdx.x];
  }
  __syncthreads();

  const float4* q4 = (const float4*)(q + ((size_t)b * S_ + pos) * D_);
  const float4* v4 = (const float4*)(v + ((size_t)b * S_ + pos) * D_);
  uint2* qw = (uint2*)(qb   + ((size_t)b * S_ + pos) * D_);
  uint2* vw = (uint2*)(vbuf + ((size_t)b * S_ + pos) * D_);

  float acc[64];
  #pragma unroll
  for (int i = 0; i < 64; i++) acc[i] = 0.f;
  float ss = 0.f;

  #pragma unroll 4
  for (int c = 0; c < 16; c++){
    float4 wa = q4[c];
    float4 xa = v4[c];
    ss += wa.x*wa.x + wa.y*wa.y + wa.z*wa.z + wa.w*wa.w;
    qw[c] = make_uint2(pk2bf(wa.x, wa.y), pk2bf(wa.z, wa.w));
    vw[c] = make_uint2(pk2bf(xa.x, xa.y), pk2bf(xa.z, xa.w));
    float qa[4] = {wa.x, wa.y, wa.z, wa.w};
    #pragma unroll
    for (int dd = 0; dd < 4; dd++){
      int d = c * 4 + dd;
      const float4* Rr = (const float4*)(&Rl[d * 64]);
      #pragma unroll
      for (int k4 = 0; k4 < 16; k4++){
        float4 rv = Rr[k4];      // broadcast (same addr all lanes) — conflict-free
        acc[k4*4+0] += qa[dd] * rv.x;
        acc[k4*4+1] += qa[dd] * rv.y;
        acc[k4*4+2] += qa[dd] * rv.z;
        acc[k4*4+3] += qa[dd] * rv.w;
      }
    }
  }
  scq[(size_t)b * S_ + pos] = rsqrtf(fmaxf(ss, 1e-12f)) * 0.125f;

  #pragma unroll
  for (int r = 0; r < 4; r++){
    float bv = acc[r*16]; int bi = 0;
    #pragma unroll
    for (int m = 1; m < 32; m++){
      float vv = (m < 16) ? acc[r*16 + m] : -acc[r*16 + m - 16];
      if (vv > bv){ bv = vv; bi = m; }   // strict >: first max wins
    }
    hout[((size_t)b * NR_ + r) * S_ + pos] = bi;
  }
}

// ---------------------------------------------------------------------------
// K2: stable counting sort on 32 bins per (b,r).
// ---------------------------------------------------------------------------
__global__ __launch_bounds__(256) void k_sort(const int* __restrict__ h,
                                              int* __restrict__ sidx,
                                              int* __restrict__ chk){
  __shared__ int cnt[32][257];
  __shared__ int base[32];
  int br = blockIdx.x;
  const int* hb = h + (size_t)br * S_;
  int t = threadIdx.x;

  #pragma unroll
  for (int hh = 0; hh < 32; hh++) cnt[hh][t] = 0;
  __syncthreads();

  int hv[8];
  const int4* hb4 = (const int4*)hb;
  int4 a0 = hb4[t*2], a1 = hb4[t*2+1];
  hv[0]=a0.x; hv[1]=a0.y; hv[2]=a0.z; hv[3]=a0.w;
  hv[4]=a1.x; hv[5]=a1.y; hv[6]=a1.z; hv[7]=a1.w;
  #pragma unroll
  for (int k = 0; k < 8; k++) cnt[hv[k]][t]++;
  __syncthreads();

  int wave = t >> 6, lane = t & 63;
  for (int hh = wave*8; hh < wave*8 + 8; hh++){
    int vals[4]; int s0 = 0;
    #pragma unroll
    for (int k = 0; k < 4; k++){ vals[k] = cnt[hh][lane*4+k]; s0 += vals[k]; }
    int incl = s0;
    #pragma unroll
    for (int off = 1; off < 64; off <<= 1){
      int o = __shfl_up(incl, off, 64);
      if (lane >= off) incl += o;
    }
    int run = incl - s0;
    #pragma unroll
    for (int k = 0; k < 4; k++){ int tmp = vals[k]; cnt[hh][lane*4+k] = run; run += tmp; }
    if (lane == 63) base[hh] = incl;
  }
  __syncthreads();
  if (t == 0){
    int run = 0;
    #pragma unroll
    for (int hh = 0; hh < 32; hh++){ int tot = base[hh]; base[hh] = run; run += tot; }
  }
  __syncthreads();

  int p0 = t * 8;
  #pragma unroll
  for (int k = 0; k < 8; k++){
    int hh = hv[k];
    int c = cnt[hh][t];
    int slot = base[hh] + c;
    cnt[hh][t] = c + 1;
    sidx[(size_t)br * S_ + slot]    = p0 + k;
    chk [(size_t)br * S_ + p0 + k]  = slot >> 6;
  }
}

// ---------------------------------------------------------------------------
// K3: per (b, r, bucket n): MFMA attention on pre-converted bf16 q/v.
// S^T via MFMA (col=i query, regs=j keys): softmax runs entirely on the f32
// accumulators in registers (no logit LDS round-trip); per-(i,jtile) partial
// (max,sum) reduced via shfl + 4x64 LDS arrays; probs written to SM once.
// Phase 5 computes out^T (Vt rows A, P rows B) -> vectorized scatter.
// ---------------------------------------------------------------------------
__global__ __launch_bounds__(256, 3) void k_attn(const u16* __restrict__ qb,
                                                 const u16* __restrict__ vb,
                                                 const int* __restrict__ sidx,
                                                 const int* __restrict__ chk,
                                                 const float* __restrict__ scq,
                                                 float* __restrict__ lse_ws,
                                                 u16*  __restrict__ att_ws){
  __shared__ u16 A[128*AS];      // Q/K tile row-major; later Vt[64][VS] (d-major)
  __shared__ u16 SM[64*PS];      // probabilities (bf16), row i, col j
  __shared__ int   pkey[128];
  __shared__ float rcnt[128];
  __shared__ float sc[128];
  __shared__ float pm[4*64];     // per (jtile, i) partial max
  __shared__ float ps[4*64];     // per (jtile, i) partial sum

  int blk = blockIdx.x;
  int b = blk >> 7, r = (blk >> 5) & 3, n = blk & 31;
  int npv = (n + 31) & 31;
  int t = threadIdx.x;
  int lane = t & 63, w = t >> 6;
  int la = lane & 31, hh = lane >> 5;
  int coff = hh * 8;
  const int* sb = sidx + ((size_t)b * NR_ + r) * S_;

  if (t < 128){
    int p = (t < 64) ? sb[npv*64 + t] : sb[n*64 + (t - 64)];
    pkey[t] = p;
    int c = 0;
    #pragma unroll
    for (int rr = 0; rr < 4; rr++){
      int ch = chk[((size_t)b * NR_ + rr) * S_ + p];
      c += (ch == n) || (ch == npv);
    }
    if (c < 1) c = 1;
    rcnt[t] = 1.0f / (float)c;
    sc[t] = scq[(size_t)b * S_ + p];
  }
  __syncthreads();

  // ---- phase 1: stage Q/K bf16 rows; early V column gather ----------------
  {
    int row = t >> 1, half = t & 1;
    const uint4* src = (const uint4*)(qb + ((size_t)b*S_ + pkey[row])*D_) + half*4;
    uint4* dst = (uint4*)(&A[row*AS + half*32]);
    #pragma unroll
    for (int k = 0; k < 4; k++) dst[k] = src[k];
  }
  int jp = t & 63, dgrp = t >> 6;   // V: key pair (2jp,2jp+1), d-range dgrp*16..+15
  uint4 va0, va1, vb0, vb1;
  {
    const uint4* s0 = (const uint4*)(vb + ((size_t)b*S_ + pkey[2*jp  ])*D_ + dgrp*16);
    const uint4* s1 = (const uint4*)(vb + ((size_t)b*S_ + pkey[2*jp+1])*D_ + dgrp*16);
    va0 = s0[0]; va1 = s0[1]; vb0 = s1[0]; vb1 = s1[1];
  }
  __syncthreads();

  // ---- phase 2: S^T = K.Q^T via MFMA; mask+exp in registers; partials -----
  float e0[16], e1[16];            // exp(x - m_loc), live across the barrier
  float ml0, ml1;                  // per-lane local maxima
  {
    int jt = w;                         // j-tile 0..3
    f32x16 acc0, acc1;                  // i = la, i = 32+la
    #pragma unroll
    for (int i = 0; i < 16; i++){ acc0[i] = 0.f; acc1[i] = 0.f; }
    int arow  = (jt*32 + la) * AS;      // K row j
    int brow0 = (64 + la) * AS;         // Q row i (0..31)
    int brow1 = (96 + la) * AS;         // Q row i (32..63)
    #pragma unroll
    for (int ks = 0; ks < 4; ks++){
      int o = ks*16 + coff;
      bf16x8 af = ld8(&A[arow  + o]);
      bf16x8 b0 = ld8(&A[brow0 + o]);
      bf16x8 b1 = ld8(&A[brow1 + o]);
      acc0 = __builtin_amdgcn_mfma_f32_32x32x16_bf16(af, b0, acc0, 0, 0, 0);
      acc1 = __builtin_amdgcn_mfma_f32_32x32x16_bf16(af, b1, acc1, 0, 0, 0);
    }
    int pj[16]; float scj[16];
    #pragma unroll
    for (int g = 0; g < 4; g++){
      int j0 = jt*32 + g*8 + 4*hh;
      #pragma unroll
      for (int m = 0; m < 4; m++){ pj[g*4+m] = pkey[j0+m]; scj[g*4+m] = sc[j0+m]; }
    }
    int pi0 = pkey[64 + la], pi1 = pkey[96 + la];
    float x0[16], x1[16];
    #pragma unroll
    for (int reg = 0; reg < 16; reg++){
      float a0v = acc0[reg] * scj[reg];
      float a1v = acc1[reg] * scj[reg];
      if (pi0 < pj[reg]) a0v = -1000000000.0f; else if (pi0 == pj[reg]) a0v = -100000.0f;
      if (pi1 < pj[reg]) a1v = -1000000000.0f; else if (pi1 == pj[reg]) a1v = -100000.0f;
      x0[reg] = a0v; x1[reg] = a1v;
    }
    ml0 = x0[0]; ml1 = x1[0];
    #pragma unroll
    for (int reg = 1; reg < 16; reg++){ ml0 = fmaxf(ml0, x0[reg]); ml1 = fmaxf(ml1, x1[reg]); }
    float s0 = 0.f, s1 = 0.f;
    #pragma unroll
    for (int reg = 0; reg < 16; reg++){
      e0[reg] = __expf(x0[reg] - ml0); s0 += e0[reg];
      e1[reg] = __expf(x1[reg] - ml1); s1 += e1[reg];
    }
    // combine the two hh halves (same i, disjoint j) within the wave
    float om0 = __shfl_xor(ml0, 32, 64), os0 = __shfl_xor(s0, 32, 64);
    float om1 = __shfl_xor(ml1, 32, 64), os1 = __shfl_xor(s1, 32, 64);
    float m20 = fmaxf(ml0, om0);
    float m21 = fmaxf(ml1, om1);
    float s20 = s0 * __expf(ml0 - m20) + os0 * __expf(om0 - m20);
    float s21 = s1 * __expf(ml1 - m21) + os1 * __expf(om1 - m21);
    if (hh == 0){
      pm[jt*64 + la]      = m20;  ps[jt*64 + la]      = s20;
      pm[jt*64 + 32 + la] = m21;  ps[jt*64 + 32 + la] = s21;
    }
  }
  __syncthreads();

  // ---- phase 3: finalize softmax from partials, write probs; Vt build -----
  {
    int jt = w;
    // global (m, s) for i = la and i = 32+la
    float mg0 = pm[la],      mg1 = pm[32 + la];
    #pragma unroll
    for (int k = 1; k < 4; k++){
      mg0 = fmaxf(mg0, pm[k*64 + la]);
      mg1 = fmaxf(mg1, pm[k*64 + 32 + la]);
    }
    float sg0 = 0.f, sg1 = 0.f;
    #pragma unroll
    for (int k = 0; k < 4; k++){
      sg0 += ps[k*64 + la]      * __expf(pm[k*64 + la]      - mg0);
      sg1 += ps[k*64 + 32 + la] * __expf(pm[k*64 + 32 + la] - mg1);
    }
    float f0 = __expf(ml0 - mg0) / sg0;
    float f1 = __expf(ml1 - mg1) / sg1;
    #pragma unroll
    for (int g = 0; g < 4; g++){
      int j0 = jt*32 + g*8 + 4*hh;
      float4 rc = *(const float4*)(&rcnt[j0]);
      float p00 = e0[g*4+0]*f0*rc.x, p01 = e0[g*4+1]*f0*rc.y;
      float p02 = e0[g*4+2]*f0*rc.z, p03 = e0[g*4+3]*f0*rc.w;
      float p10 = e1[g*4+0]*f1*rc.x, p11 = e1[g*4+1]*f1*rc.y;
      float p12 = e1[g*4+2]*f1*rc.z, p13 = e1[g*4+3]*f1*rc.w;
      *(uint2*)(&SM[la*PS + j0])        = make_uint2(pk2bf(p00,p01), pk2bf(p02,p03));
      *(uint2*)(&SM[(32+la)*PS + j0])   = make_uint2(pk2bf(p10,p11), pk2bf(p12,p13));
    }
    if (w == 0 && hh == 0){
      lse_ws[((size_t)b*S_ + pkey[64 + la])*NR_ + r] = mg0 + __logf(sg0);
      lse_ws[((size_t)b*S_ + pkey[96 + la])*NR_ + r] = mg1 + __logf(sg1);
    }
  }
  { // Vt = V^T (pure bf16 interleave), overwriting A (reads done pre-barrier)
    u32 au[8] = {va0.x, va0.y, va0.z, va0.w, va1.x, va1.y, va1.z, va1.w};
    u32 bu[8] = {vb0.x, vb0.y, vb0.z, vb0.w, vb1.x, vb1.y, vb1.z, vb1.w};
    u32* vtp = (u32*)A;
    #pragma unroll
    for (int k = 0; k < 8; k++){
      int d0 = dgrp*16 + 2*k;
      u32 even = (au[k] & 0xffffu) | (bu[k] << 16);
      u32 odd  = (au[k] >> 16)     | (bu[k] & 0xffff0000u);
      vtp[ d0      * (VS/2) + jp] = even;
      vtp[(d0 + 1) * (VS/2) + jp] = odd;
    }
  }
  __syncthreads();

  // ---- phase 5: out^T = Vt.P^T via MFMA (M=d, N=i), vectorized scatter ----
  {
    int Mt2 = w >> 1, Nt2 = w & 1;
    f32x16 acc;
    #pragma unroll
    for (int i = 0; i < 16; i++) acc[i] = 0.f;
    int arow = (Mt2*32 + la) * VS;      // Vt row d, j contig
    int brow = (Nt2*32 + la) * PS;      // P row i, j contig
    #pragma unroll
    for (int ks = 0; ks < 8; ks++){
      int o = ks*16 + coff;
      bf16x8 af = ld8(&A[arow + o]);
      bf16x8 bf = ld8(&SM[brow + o]);
      acc = __builtin_amdgcn_mfma_f32_32x32x16_bf16(af, bf, acc, 0, 0, 0);
    }
    // C col = i (lane), rows = d (regs, 4 groups of 4 contiguous)
    int i = Nt2*32 + la;
    int p = pkey[64 + i];
    u16* base = att_ws + (((size_t)b*S_ + p)*NR_ + r)*D_ + Mt2*32 + 4*hh;
    #pragma unroll
    for (int g = 0; g < 4; g++){
      uint2 val = make_uint2(pk2bf(acc[4*g+0], acc[4*g+1]),
                             pk2bf(acc[4*g+2], acc[4*g+3]));
      *(uint2*)(base + g*8) = val;
    }
  }
}

// ---------------------------------------------------------------------------
// K4: per position softmax over round LSEs, weighted sum of round outputs.
// 4 outputs per thread (uint2 att reads, float4 out writes). grid 4096.
// ---------------------------------------------------------------------------
__global__ __launch_bounds__(256) void k_comb(const float* __restrict__ lse_ws,
                                              const u16* __restrict__ att_ws,
                                              float* __restrict__ out){
  size_t idx4 = (size_t)blockIdx.x * 256 + threadIdx.x;  // over B*S*D/4
  size_t pd = idx4 >> 4;
  int d0 = (int)(idx4 & 15) * 4;
  float4 lv = *(const float4*)(lse_ws + pd * 4);
  float m = fmaxf(fmaxf(lv.x, lv.y), fmaxf(lv.z, lv.w));
  float e0 = __expf(lv.x - m), e1 = __expf(lv.y - m);
  float e2 = __expf(lv.z - m), e3 = __expf(lv.w - m);
  float inv = 1.0f / (e0 + e1 + e2 + e3);
  e0 *= inv; e1 *= inv; e2 *= inv; e3 *= inv;
  const u16* a = att_ws + pd * 256 + d0;
  uint2 u0 = *(const uint2*)(a);
  uint2 u1 = *(const uint2*)(a + 64);
  uint2 u2 = *(const uint2*)(a + 128);
  uint2 u3 = *(const uint2*)(a + 192);
  float4 o;
  float a0,b0,a1,b1,a2,b2,a3,b3;
  unpack2(u0.x,a0,b0); unpack2(u1.x,a1,b1); unpack2(u2.x,a2,b2); unpack2(u3.x,a3,b3);
  o.x = a0*e0 + a1*e1 + a2*e2 + a3*e3;
  o.y = b0*e0 + b1*e1 + b2*e2 + b3*e3;
  unpack2(u0.y,a0,b0); unpack2(u1.y,a1,b1); unpack2(u2.y,a2,b2); unpack2(u3.y,a3,b3);
  o.z = a0*e0 + a1*e1 + a2*e2 + a3*e3;
  o.w = b0*e0 + b1*e1 + b2*e2 + b3*e3;
  *(float4*)(out + pd * D_ + d0) = o;
}

// ---------------------------------------------------------------------------
extern "C" void kernel_launch(void* const* d_in, const int* in_sizes, int n_in,
                              void* d_out, int out_size, void* d_ws, size_t ws_size,
                              hipStream_t stream){
  const float* q = (const float*)d_in[0];   // (32,2048,64) f32
  const float* v = (const float*)d_in[1];   // (32,2048,64) f32
  const float* R = (const float*)d_in[2];   // (32,64,4,16) f32

  char* w = (char*)d_ws;
  int*   h    = (int*)  (w + 0);                     // 1 MB
  int*   sidx = (int*)  (w + (size_t)(1u << 20));    // 1 MB
  int*   chkA = (int*)  (w + (size_t)(2u << 20));    // 1 MB
  float* lse  = (float*)(w + (size_t)(3u << 20));    // 1 MB
  u16*   att  = (u16*)  (w + (size_t)(4u << 20));    // 32 MB
  u16*   qb   = (u16*)  (w + (size_t)(36u << 20));   // 8 MB bf16 q
  u16*   vbuf = (u16*)  (w + (size_t)(44u << 20));   // 8 MB bf16 v
  float* scq  = (float*)(w + (size_t)(52u << 20));   // 256 KB
  float* out  = (float*)d_out;

  k_hash <<<256,  256, 0, stream>>>(q, v, R, h, qb, vbuf, scq);
  k_sort <<<128,  256, 0, stream>>>(h, sidx, chkA);
  k_attn <<<4096, 256, 0, stream>>>(qb, vbuf, sidx, chkA, scq, lse, att);
  k_comb <<<4096, 256, 0, stream>>>(lse, att, out);
}